// Round 3
// baseline (1492.372 us; speedup 1.0000x reference)
//
#include <hip/hip_runtime.h>
#include <hip/hip_fp16.h>

#define ITERS 100
#define AGENT __HIP_MEMORY_SCOPE_AGENT

// ---- workspace layout (4-byte units) ----
// [0..31]    fr[2][16]  row-stripe flags (monotone counters, memset to 0)
// [32..63]   fc[2][16]  col-stripe flags
// [64..]     rpart[2][16][16][136]  u-phase partials: [buf][bi][src_bj][row 0..127, 128=vsum]
// then       cpart[2][16][16][136]  v-phase partials: [buf][bj][src_bi][col 0..127, 128=usum]
// then       per-block u/v scratch: 272 floats per block
#define SLOT   136
#define PART   (2 * 16 * 16 * SLOT)
#define RP_OFF 64
#define CP_OFF (RP_OFF + PART)
#define UV_OFF (CP_OFF + PART)

__device__ __forceinline__ float wave_sum(float p) {
    p += __shfl_xor(p, 1, 64);
    p += __shfl_xor(p, 2, 64);
    p += __shfl_xor(p, 4, 64);
    p += __shfl_xor(p, 8, 64);
    p += __shfl_xor(p, 16, 64);
    p += __shfl_xor(p, 32, 64);
    return p;
}

__global__ void __launch_bounds__(256, 1)
sinkhorn_fused(const float* __restrict__ Q, const float* __restrict__ R,
               const float* __restrict__ zp, float* __restrict__ out,
               unsigned* __restrict__ ws)
{
    // 64 KiB LDS. GEMM staging first, then the two fp16 tile copies.
    __shared__ __align__(16) char smem[65536];
    float* As = (float*)smem;               // [2][32][128] k-major A slabs
    float* Bs = (float*)(smem + 32768);     // [2][32][128] k-major B slabs
    char*  TrmB = smem;                     // [128 rows][16 chunks of 16B], chunk-swizzled
    char*  TcmB = smem + 32768;             // [128 cols][16 chunks of 16B], chunk-swizzled

    const int t  = threadIdx.x;
    const int b  = blockIdx.x;
    const int bi = b >> 4, bj = b & 15;
    const int tx = t & 15, ty = t >> 4;
    const int l  = t & 63, w  = t >> 6;
    const int gi0 = bi * 128, gj0 = bj * 128;

    // ---------------- phase 1: 128x128 score tile, fp32 GEMM K=512 ----------------
    float acc[8][8];
#pragma unroll
    for (int r = 0; r < 8; r++)
#pragma unroll
        for (int c = 0; c < 8; c++) acc[r][c] = 0.f;

    const int lr = t & 31, lc4 = t >> 5;
    const float* Qb = Q + (size_t)gi0 * 512;
    const float* Rb = R + (size_t)gj0 * 512;

    float4 qa[4], ra[4];
#pragma unroll
    for (int i = 0; i < 4; i++) {
        qa[i] = *(const float4*)(Qb + (size_t)(lr + 32 * i) * 512 + 4 * lc4);
        ra[i] = *(const float4*)(Rb + (size_t)(lr + 32 * i) * 512 + 4 * lc4);
    }
#pragma unroll
    for (int i = 0; i < 4; i++) {
        int row = lr + 32 * i;
        As[(4*lc4+0)*128 + row] = qa[i].x;  As[(4*lc4+1)*128 + row] = qa[i].y;
        As[(4*lc4+2)*128 + row] = qa[i].z;  As[(4*lc4+3)*128 + row] = qa[i].w;
        Bs[(4*lc4+0)*128 + row] = ra[i].x;  Bs[(4*lc4+1)*128 + row] = ra[i].y;
        Bs[(4*lc4+2)*128 + row] = ra[i].z;  Bs[(4*lc4+3)*128 + row] = ra[i].w;
    }
    __syncthreads();

    for (int ks = 0; ks < 16; ks++) {
        if (ks < 15) {
            int k0 = (ks + 1) * 32;
#pragma unroll
            for (int i = 0; i < 4; i++) {
                qa[i] = *(const float4*)(Qb + (size_t)(lr+32*i)*512 + k0 + 4*lc4);
                ra[i] = *(const float4*)(Rb + (size_t)(lr+32*i)*512 + k0 + 4*lc4);
            }
        }
        const float* A = As + (ks & 1) * (32 * 128);
        const float* B = Bs + (ks & 1) * (32 * 128);
#pragma unroll 4
        for (int k = 0; k < 32; k++) {
            float4 a0 = *(const float4*)(A + k*128 + 8*ty);
            float4 a1 = *(const float4*)(A + k*128 + 8*ty + 4);
            float4 b0 = *(const float4*)(B + k*128 + 8*tx);
            float4 b1 = *(const float4*)(B + k*128 + 8*tx + 4);
            float av[8] = {a0.x,a0.y,a0.z,a0.w,a1.x,a1.y,a1.z,a1.w};
            float bv[8] = {b0.x,b0.y,b0.z,b0.w,b1.x,b1.y,b1.z,b1.w};
#pragma unroll
            for (int r = 0; r < 8; r++)
#pragma unroll
                for (int c = 0; c < 8; c++)
                    acc[r][c] = fmaf(av[r], bv[c], acc[r][c]);
        }
        if (ks < 15) {
            __syncthreads();
            float* An = As + ((ks+1) & 1) * (32 * 128);
            float* Bn = Bs + ((ks+1) & 1) * (32 * 128);
#pragma unroll
            for (int i = 0; i < 4; i++) {
                int row = lr + 32 * i;
                An[(4*lc4+0)*128 + row] = qa[i].x;  An[(4*lc4+1)*128 + row] = qa[i].y;
                An[(4*lc4+2)*128 + row] = qa[i].z;  An[(4*lc4+3)*128 + row] = qa[i].w;
                Bn[(4*lc4+0)*128 + row] = ra[i].x;  Bn[(4*lc4+1)*128 + row] = ra[i].y;
                Bn[(4*lc4+2)*128 + row] = ra[i].z;  Bn[(4*lc4+3)*128 + row] = ra[i].w;
            }
            __syncthreads();
        }
    }
    __syncthreads();                        // As/Bs dead; LDS becomes Trm/Tcm

    // ---------------- phase 2: K0 = exp(score*10) -> swizzled fp16 tiles ----------------
    // Element (i,j): logical chunk c=j/8 stored at physical chunk c^(i&15).
    const float E = expf(zp[0] * 10.0f);
#pragma unroll
    for (int r = 0; r < 8; r++)
#pragma unroll
        for (int c = 0; c < 8; c++) acc[r][c] = expf(acc[r][c] * 10.0f);

#pragma unroll
    for (int r = 0; r < 8; r++) {           // row-major tile: one 16B chunk per row
        int rr = 8 * ty + r;
        unsigned short h[8];
#pragma unroll
        for (int c = 0; c < 8; c++) h[c] = __half_as_ushort(__float2half(acc[r][c]));
        uint4 pk;
        pk.x = h[0] | ((unsigned)h[1] << 16); pk.y = h[2] | ((unsigned)h[3] << 16);
        pk.z = h[4] | ((unsigned)h[5] << 16); pk.w = h[6] | ((unsigned)h[7] << 16);
        *(uint4*)(TrmB + rr * 256 + ((tx ^ (rr & 15)) << 4)) = pk;
    }
#pragma unroll
    for (int c = 0; c < 8; c++) {           // col-major tile
        int cc = 8 * tx + c;
        unsigned short h[8];
#pragma unroll
        for (int r = 0; r < 8; r++) h[r] = __half_as_ushort(__float2half(acc[r][c]));
        uint4 pk;
        pk.x = h[0] | ((unsigned)h[1] << 16); pk.y = h[2] | ((unsigned)h[3] << 16);
        pk.z = h[4] | ((unsigned)h[5] << 16); pk.w = h[6] | ((unsigned)h[7] << 16);
        *(uint4*)(TcmB + cc * 256 + ((ty ^ (cc & 15)) << 4)) = pk;
    }

    // ---------------- scratch pointers + init ----------------
    unsigned* fr    = ws;                   // [2][16]
    unsigned* fc    = ws + 32;              // [2][16]
    unsigned* rpart = ws + RP_OFF;
    unsigned* cpart = ws + CP_OFF;
    float* uvb  = (float*)(ws + UV_OFF) + b * 272;
    float* ubuf = uvb;                      // [0..127] u, [128..129] wave partial sums
    float* vbuf = uvb + 136;                // [0..127] v, [128..129] wave partial sums

    if (t < 128)      vbuf[t] = 1.0f;
    else if (t < 130) vbuf[t] = 64.0f;      // vbuf[128]+vbuf[129] = 128 = initial vsum
    float uN = 0.f, vN = 1.0f, vsum = 128.0f, usum = 0.f;
    __syncthreads();                        // tiles + vbuf ready

    const int i2 = t >> 1, half = t & 1;    // matvec: thread pair per row/col

    // ---------------- phase 3: 100 Sinkhorn iterations ----------------
    for (int it = 0; it < ITERS; it++) {
        const int buf = it & 1;
        const unsigned target = 16u * (unsigned)(it / 2 + 1);

        // ======== u-phase: r_i = sum_j K[i,j] v_j ========
        {
            unsigned* base = rpart + ((buf * 16 + bi) * 16) * SLOT;
            // matvec over half a row per thread
            {
                const char* rp = TrmB + i2 * 256;
                const float4* v4 = (const float4*)vbuf;
                float p = 0.f;
#pragma unroll
                for (int k = 0; k < 8; k++) {
                    int c = 2 * k + half;
                    uint4 kq = *(const uint4*)(rp + ((c ^ (i2 & 15)) << 4));
                    float4 va = v4[2 * c], vb = v4[2 * c + 1];
                    const __half2* h2 = (const __half2*)&kq;
                    float2 f;
                    f = __half22float2(h2[0]); p = fmaf(f.x, va.x, fmaf(f.y, va.y, p));
                    f = __half22float2(h2[1]); p = fmaf(f.x, va.z, fmaf(f.y, va.w, p));
                    f = __half22float2(h2[2]); p = fmaf(f.x, vb.x, fmaf(f.y, vb.y, p));
                    f = __half22float2(h2[3]); p = fmaf(f.x, vb.z, fmaf(f.y, vb.w, p));
                }
                p += __shfl_xor(p, 1, 64);
                if (half == 0)
                    __hip_atomic_store(base + bj * SLOT + i2, __float_as_uint(p),
                                       __ATOMIC_RELAXED, AGENT);
                if (t == 255)
                    __hip_atomic_store(base + bj * SLOT + 128, __float_as_uint(vsum),
                                       __ATOMIC_RELAXED, AGENT);
            }
            __builtin_amdgcn_s_waitcnt(0);  // this wave's posts complete
            __syncthreads();                // all waves' posts drained (vmcnt(0) pre-barrier)
            if (t == 0) {
                unsigned old = __hip_atomic_fetch_add(&fr[buf * 16 + bi], 1u,
                                                      __ATOMIC_RELAXED, AGENT);
                if (old + 1 < target)
                    while (__hip_atomic_load(&fr[buf * 16 + bi],
                                             __ATOMIC_RELAXED, AGENT) < target)
                        __builtin_amdgcn_s_sleep(2);
            }
            __syncthreads();                // flag reached 16k: all 16 posts visible
            // batched single read
            float rsum = 0.f, ssum = 0.f;
            if (t < 128) {
#pragma unroll
                for (int s = 0; s < 16; s++)
                    rsum += __uint_as_float(__hip_atomic_load(base + s * SLOT + t,
                                                              __ATOMIC_RELAXED, AGENT));
            }
#pragma unroll
            for (int s = 0; s < 16; s++)
                ssum += __uint_as_float(__hip_atomic_load(base + s * SLOT + 128,
                                                          __ATOMIC_RELAXED, AGENT));
            float nuN = 1.0f / (E * (ssum + vN));   // augmented all-E row, exact
            if (t < 128) {
                float ui = 1.0f / (rsum + E * vN);
                ubuf[t] = ui;
                float wsm = wave_sum(ui);
                if (l == 0) ubuf[128 + w] = wsm;
            }
            uN = nuN;
            __syncthreads();                // ubuf complete
            usum = ubuf[128] + ubuf[129];
        }

        // ======== v-phase: c_j = sum_i K[i,j] u_i ========
        {
            unsigned* base = cpart + ((buf * 16 + bj) * 16) * SLOT;
            {
                const char* cp = TcmB + i2 * 256;
                const float4* u4 = (const float4*)ubuf;
                float p = 0.f;
#pragma unroll
                for (int k = 0; k < 8; k++) {
                    int c = 2 * k + half;
                    uint4 kq = *(const uint4*)(cp + ((c ^ (i2 & 15)) << 4));
                    float4 ua = u4[2 * c], ub = u4[2 * c + 1];
                    const __half2* h2 = (const __half2*)&kq;
                    float2 f;
                    f = __half22float2(h2[0]); p = fmaf(f.x, ua.x, fmaf(f.y, ua.y, p));
                    f = __half22float2(h2[1]); p = fmaf(f.x, ua.z, fmaf(f.y, ua.w, p));
                    f = __half22float2(h2[2]); p = fmaf(f.x, ub.x, fmaf(f.y, ub.y, p));
                    f = __half22float2(h2[3]); p = fmaf(f.x, ub.z, fmaf(f.y, ub.w, p));
                }
                p += __shfl_xor(p, 1, 64);
                if (half == 0)
                    __hip_atomic_store(base + bi * SLOT + i2, __float_as_uint(p),
                                       __ATOMIC_RELAXED, AGENT);
                if (t == 255)
                    __hip_atomic_store(base + bi * SLOT + 128, __float_as_uint(usum),
                                       __ATOMIC_RELAXED, AGENT);
            }
            __builtin_amdgcn_s_waitcnt(0);
            __syncthreads();
            if (t == 0) {
                unsigned old = __hip_atomic_fetch_add(&fc[buf * 16 + bj], 1u,
                                                      __ATOMIC_RELAXED, AGENT);
                if (old + 1 < target)
                    while (__hip_atomic_load(&fc[buf * 16 + bj],
                                             __ATOMIC_RELAXED, AGENT) < target)
                        __builtin_amdgcn_s_sleep(2);
            }
            __syncthreads();
            float csum = 0.f, ssum = 0.f;
            if (t < 128) {
#pragma unroll
                for (int s = 0; s < 16; s++)
                    csum += __uint_as_float(__hip_atomic_load(base + s * SLOT + t,
                                                              __ATOMIC_RELAXED, AGENT));
            }
#pragma unroll
            for (int s = 0; s < 16; s++)
                ssum += __uint_as_float(__hip_atomic_load(base + s * SLOT + 128,
                                                          __ATOMIC_RELAXED, AGENT));
            float nvN = 1.0f / (E * (ssum + uN));   // augmented all-E col
            if (t < 128) {
                float vj = 1.0f / (csum + E * uN);
                vbuf[t] = vj;
                float wsm = wave_sum(vj);
                if (l == 0) vbuf[128 + w] = wsm;
            }
            vN = nvN;
            __syncthreads();                // vbuf complete
            vsum = vbuf[128] + vbuf[129];
        }
    }

    // ---------------- phase 4: epilogue P = u_i K0 v_j ----------------
    float* P  = out;                        // [2048][2048]
    float* PA = out + (size_t)2048 * 2048;  // [2049][2049]
    float2 vv = *(const float2*)&vbuf[2 * l];
#pragma unroll 2
    for (int rr2 = 0; rr2 < 32; rr2++) {
        int i = 32 * w + rr2;
        float ui = ubuf[i];
        const char* rp = TrmB + i * 256;
        int c = l >> 2;                     // logical chunk of col 2l
        __half2 h2 = *(const __half2*)(rp + ((c ^ (i & 15)) << 4) + (l & 3) * 4);
        float2 kf = __half22float2(h2);
        float p0 = ui * kf.x * vv.x;
        float p1 = ui * kf.y * vv.y;
        size_t gi = (size_t)(gi0 + i);
        *(float2*)&P[gi * 2048 + gj0 + 2 * l] = make_float2(p0, p1);
        PA[gi * 2049 + gj0 + 2 * l]     = p0;
        PA[gi * 2049 + gj0 + 2 * l + 1] = p1;
        if (bj == 15 && l == 0) PA[gi * 2049 + 2048] = ui * E * vN;     // last col
    }
    if (bi == 15 && w == 0) {               // last row + corner
        PA[(size_t)2048 * 2049 + gj0 + 2 * l]     = uN * E * vv.x;
        PA[(size_t)2048 * 2049 + gj0 + 2 * l + 1] = uN * E * vv.y;
        if (bj == 15 && l == 0) PA[(size_t)2048 * 2049 + 2048] = uN * E * vN;
    }
}

extern "C" void kernel_launch(void* const* d_in, const int* in_sizes, int n_in,
                              void* d_out, int out_size, void* d_ws, size_t ws_size,
                              hipStream_t stream)
{
    (void)in_sizes; (void)n_in; (void)out_size; (void)ws_size;
    const float* Q  = (const float*)d_in[0];
    const float* R  = (const float*)d_in[1];
    const float* zp = (const float*)d_in[2];
    float* out = (float*)d_out;
    unsigned* ws = (unsigned*)d_ws;
    // zero the 64 monotone stripe-flag counters (harness poisons ws with 0xAA)
    hipMemsetAsync(d_ws, 0, 64 * sizeof(unsigned), stream);
    void* args[] = { (void*)&Q, (void*)&R, (void*)&zp, (void*)&out, (void*)&ws };
    // 256 blocks == 256 CUs, 64 KiB LDS, 1 block/CU -> co-resident for spin-wait.
    hipLaunchCooperativeKernel((const void*)sinkhorn_fused, dim3(256), dim3(256),
                               args, 0, stream);
}

// Round 4
// 976.612 us; speedup vs baseline: 1.5281x; 1.5281x over previous
//
#include <hip/hip_runtime.h>
#include <hip/hip_fp16.h>

#define ITERS 100
#define AGENT __HIP_MEMORY_SCOPE_AGENT

// 8-byte message: fp32 value + iteration tag, moved as ONE relaxed agent-scope
// atomic. Tag==it+1 validates the value (poison 0xAAAAAAAA never matches).
// Poll-is-read: observing the tag IS both detection and data delivery -> the
// phase critical path is a single coherent hop (store visible -> load sees it).
union PK { unsigned long long u; struct { float v; unsigned tag; } s; };

// ws layout (8-byte units):
//   rmsg[2][16][16][136] : u-phase, [buf][bi][src_bj][row 0..127, 128 = src stripe vsum]
//   cmsg[2][16][16][136] : v-phase, [buf][bj][src_bi][col 0..127, 128 = src stripe usum]
//   then per-block fp32 u/v scratch (block-private, L1/L2-resident plain ld/st)
#define SLOT 136
#define MSG_ONE (2 * 16 * 16 * SLOT)
#define UV_STRIDE 272

__device__ __forceinline__ float wave_sum(float p) {
    p += __shfl_xor(p, 1, 64);
    p += __shfl_xor(p, 2, 64);
    p += __shfl_xor(p, 4, 64);
    p += __shfl_xor(p, 8, 64);
    p += __shfl_xor(p, 16, 64);
    p += __shfl_xor(p, 32, 64);
    return p;
}

__global__ void __launch_bounds__(256, 1)
sinkhorn_fused(const float* __restrict__ Q, const float* __restrict__ R,
               const float* __restrict__ zp, float* __restrict__ out,
               unsigned long long* __restrict__ ws)
{
    // 64 KiB LDS. GEMM staging first, then the two fp16 tile copies.
    __shared__ __align__(16) char smem[65536];
    float* As = (float*)smem;               // [2][32][128] k-major A slabs
    float* Bs = (float*)(smem + 32768);     // [2][32][128] k-major B slabs
    char*  TrmB = smem;                     // [128 rows][16 chunks of 16B], chunk-swizzled
    char*  TcmB = smem + 32768;             // [128 cols][16 chunks of 16B], chunk-swizzled

    const int t  = threadIdx.x;
    const int b  = blockIdx.x;
    const int bi = b >> 4, bj = b & 15;
    const int tx = t & 15, ty = t >> 4;
    const int l  = t & 63, w  = t >> 6;
    const int gi0 = bi * 128, gj0 = bj * 128;

    // ---------------- phase 1: 128x128 score tile, fp32 GEMM K=512 ----------------
    float acc[8][8];
#pragma unroll
    for (int r = 0; r < 8; r++)
#pragma unroll
        for (int c = 0; c < 8; c++) acc[r][c] = 0.f;

    const int lr = t & 31, lc4 = t >> 5;
    const float* Qb = Q + (size_t)gi0 * 512;
    const float* Rb = R + (size_t)gj0 * 512;

    float4 qa[4], ra[4];
#pragma unroll
    for (int i = 0; i < 4; i++) {
        qa[i] = *(const float4*)(Qb + (size_t)(lr + 32 * i) * 512 + 4 * lc4);
        ra[i] = *(const float4*)(Rb + (size_t)(lr + 32 * i) * 512 + 4 * lc4);
    }
#pragma unroll
    for (int i = 0; i < 4; i++) {
        int row = lr + 32 * i;
        As[(4*lc4+0)*128 + row] = qa[i].x;  As[(4*lc4+1)*128 + row] = qa[i].y;
        As[(4*lc4+2)*128 + row] = qa[i].z;  As[(4*lc4+3)*128 + row] = qa[i].w;
        Bs[(4*lc4+0)*128 + row] = ra[i].x;  Bs[(4*lc4+1)*128 + row] = ra[i].y;
        Bs[(4*lc4+2)*128 + row] = ra[i].z;  Bs[(4*lc4+3)*128 + row] = ra[i].w;
    }
    __syncthreads();

    for (int ks = 0; ks < 16; ks++) {
        if (ks < 15) {
            int k0 = (ks + 1) * 32;
#pragma unroll
            for (int i = 0; i < 4; i++) {
                qa[i] = *(const float4*)(Qb + (size_t)(lr+32*i)*512 + k0 + 4*lc4);
                ra[i] = *(const float4*)(Rb + (size_t)(lr+32*i)*512 + k0 + 4*lc4);
            }
        }
        const float* A = As + (ks & 1) * (32 * 128);
        const float* B = Bs + (ks & 1) * (32 * 128);
#pragma unroll 4
        for (int k = 0; k < 32; k++) {
            float4 a0 = *(const float4*)(A + k*128 + 8*ty);
            float4 a1 = *(const float4*)(A + k*128 + 8*ty + 4);
            float4 b0 = *(const float4*)(B + k*128 + 8*tx);
            float4 b1 = *(const float4*)(B + k*128 + 8*tx + 4);
            float av[8] = {a0.x,a0.y,a0.z,a0.w,a1.x,a1.y,a1.z,a1.w};
            float bv[8] = {b0.x,b0.y,b0.z,b0.w,b1.x,b1.y,b1.z,b1.w};
#pragma unroll
            for (int r = 0; r < 8; r++)
#pragma unroll
                for (int c = 0; c < 8; c++)
                    acc[r][c] = fmaf(av[r], bv[c], acc[r][c]);
        }
        if (ks < 15) {
            __syncthreads();
            float* An = As + ((ks+1) & 1) * (32 * 128);
            float* Bn = Bs + ((ks+1) & 1) * (32 * 128);
#pragma unroll
            for (int i = 0; i < 4; i++) {
                int row = lr + 32 * i;
                An[(4*lc4+0)*128 + row] = qa[i].x;  An[(4*lc4+1)*128 + row] = qa[i].y;
                An[(4*lc4+2)*128 + row] = qa[i].z;  An[(4*lc4+3)*128 + row] = qa[i].w;
                Bn[(4*lc4+0)*128 + row] = ra[i].x;  Bn[(4*lc4+1)*128 + row] = ra[i].y;
                Bn[(4*lc4+2)*128 + row] = ra[i].z;  Bn[(4*lc4+3)*128 + row] = ra[i].w;
            }
            __syncthreads();
        }
    }
    __syncthreads();                        // As/Bs dead; LDS becomes Trm/Tcm

    // ---------------- phase 2: K0 = exp(score*10) -> swizzled fp16 tiles ----------------
    // Element (i,j): logical chunk c=j/8 stored at physical chunk c^(i&15).
    const float E = expf(zp[0] * 10.0f);
#pragma unroll
    for (int r = 0; r < 8; r++)
#pragma unroll
        for (int c = 0; c < 8; c++) acc[r][c] = expf(acc[r][c] * 10.0f);

#pragma unroll
    for (int r = 0; r < 8; r++) {           // row-major tile: one 16B chunk per row
        int rr = 8 * ty + r;
        unsigned short h[8];
#pragma unroll
        for (int c = 0; c < 8; c++) h[c] = __half_as_ushort(__float2half(acc[r][c]));
        uint4 pk;
        pk.x = h[0] | ((unsigned)h[1] << 16); pk.y = h[2] | ((unsigned)h[3] << 16);
        pk.z = h[4] | ((unsigned)h[5] << 16); pk.w = h[6] | ((unsigned)h[7] << 16);
        *(uint4*)(TrmB + rr * 256 + ((tx ^ (rr & 15)) << 4)) = pk;
    }
#pragma unroll
    for (int c = 0; c < 8; c++) {           // col-major tile
        int cc = 8 * tx + c;
        unsigned short h[8];
#pragma unroll
        for (int r = 0; r < 8; r++) h[r] = __half_as_ushort(__float2half(acc[r][c]));
        uint4 pk;
        pk.x = h[0] | ((unsigned)h[1] << 16); pk.y = h[2] | ((unsigned)h[3] << 16);
        pk.z = h[4] | ((unsigned)h[5] << 16); pk.w = h[6] | ((unsigned)h[7] << 16);
        *(uint4*)(TcmB + cc * 256 + ((ty ^ (cc & 15)) << 4)) = pk;
    }

    // ---------------- scratch pointers + init ----------------
    unsigned long long* rmsg = ws;
    unsigned long long* cmsg = ws + MSG_ONE;
    float* uvb  = (float*)(ws + 2 * MSG_ONE) + b * UV_STRIDE;
    float* ubuf = uvb;                      // [0..127] u, [128..129] wave partial sums
    float* vbuf = uvb + 136;                // [0..127] v, [128..129] wave partial sums

    if (t < 128)      vbuf[t] = 1.0f;
    else if (t < 130) vbuf[t] = 64.0f;      // vbuf[128]+vbuf[129] = 128 = initial vsum
    float uN = 0.f, vN = 1.0f, vsum = 128.0f, usum = 0.f;
    __syncthreads();                        // tiles + vbuf ready

    // ---------------- phase 3: 100 Sinkhorn iterations ----------------
    for (int it = 0; it < ITERS; it++) {
        const int buf = it & 1;
        const unsigned tagw = (unsigned)(it + 1);

        // ======== u-phase: r_i = sum_j K[i,j] v_j ========
        {
            unsigned long long* base = rmsg + (size_t)((buf * 16 + bi) * 16) * SLOT;
            if (t == 128) {                 // early scalar post (no matvec dependency)
                PK p; p.s.v = vsum; p.s.tag = tagw;
                __hip_atomic_store(base + (size_t)bj * SLOT + 128, p.u, __ATOMIC_RELAXED, AGENT);
            }
            if (t < 128) {                  // full-row matvec (conflict-free swizzle)
                const char* rp = TrmB + t * 256;
                const float4* v4 = (const float4*)vbuf;
                float racc = 0.f;
#pragma unroll
                for (int c = 0; c < 16; c++) {
                    uint4 kq = *(const uint4*)(rp + ((c ^ (t & 15)) << 4));
                    float4 va = v4[2 * c], vb = v4[2 * c + 1];
                    const __half2* h2 = (const __half2*)&kq;
                    float2 f;
                    f = __half22float2(h2[0]); racc = fmaf(f.x, va.x, fmaf(f.y, va.y, racc));
                    f = __half22float2(h2[1]); racc = fmaf(f.x, va.z, fmaf(f.y, va.w, racc));
                    f = __half22float2(h2[2]); racc = fmaf(f.x, vb.x, fmaf(f.y, vb.y, racc));
                    f = __half22float2(h2[3]); racc = fmaf(f.x, vb.z, fmaf(f.y, vb.w, racc));
                }
                PK p; p.s.v = racc; p.s.tag = tagw;
                __hip_atomic_store(base + (size_t)bj * SLOT + t, p.u, __ATOMIC_RELAXED, AGENT);
            }
            // poll-is-read: waves 0,1 only (lanes<16 also gather stripe vsums)
            if (t < 128) {
                bool vdone = (l >= 16);
                float vsv = 0.f, rsum = 0.f;
                for (;;) {
                    PK m[16];
#pragma unroll
                    for (int s = 0; s < 16; s++)
                        m[s].u = __hip_atomic_load(base + (size_t)s * SLOT + t,
                                                   __ATOMIC_RELAXED, AGENT);
                    PK vm; vm.u = 0ull;
                    if (!vdone)
                        vm.u = __hip_atomic_load(base + (size_t)l * SLOT + 128,
                                                 __ATOMIC_RELAXED, AGENT);
                    int cnt = 0; float a = 0.f;
#pragma unroll
                    for (int s = 0; s < 16; s++) {
                        bool ok = (m[s].s.tag == tagw);
                        cnt += ok; a += ok ? m[s].s.v : 0.f;
                    }
                    if (!vdone && vm.s.tag == tagw) { vsv = vm.s.v; vdone = true; }
                    if (cnt == 16 && vdone) { rsum = a; break; }
                    __builtin_amdgcn_s_sleep(1);
                }
                float ssum = wave_sum(l < 16 ? vsv : 0.f);   // all-cols sum of v
                uN = 1.0f / (E * (ssum + vN));
                float ui = 1.0f / (rsum + E * vN);
                ubuf[t] = ui;
                float wsm = wave_sum(ui);
                if (l == 0) ubuf[128 + w] = wsm;
            }
            __syncthreads();                // ubuf complete (waves 2,3 parked here)
            usum = ubuf[128] + ubuf[129];
        }

        // ======== v-phase: c_j = sum_i K[i,j] u_i ========
        {
            unsigned long long* base = cmsg + (size_t)((buf * 16 + bj) * 16) * SLOT;
            if (t == 128) {
                PK p; p.s.v = usum; p.s.tag = tagw;
                __hip_atomic_store(base + (size_t)bi * SLOT + 128, p.u, __ATOMIC_RELAXED, AGENT);
            }
            if (t < 128) {
                const char* cp = TcmB + t * 256;
                const float4* u4 = (const float4*)ubuf;
                float cacc = 0.f;
#pragma unroll
                for (int c = 0; c < 16; c++) {
                    uint4 kq = *(const uint4*)(cp + ((c ^ (t & 15)) << 4));
                    float4 ua = u4[2 * c], ub = u4[2 * c + 1];
                    const __half2* h2 = (const __half2*)&kq;
                    float2 f;
                    f = __half22float2(h2[0]); cacc = fmaf(f.x, ua.x, fmaf(f.y, ua.y, cacc));
                    f = __half22float2(h2[1]); cacc = fmaf(f.x, ua.z, fmaf(f.y, ua.w, cacc));
                    f = __half22float2(h2[2]); cacc = fmaf(f.x, ub.x, fmaf(f.y, ub.y, cacc));
                    f = __half22float2(h2[3]); cacc = fmaf(f.x, ub.z, fmaf(f.y, ub.w, cacc));
                }
                PK p; p.s.v = cacc; p.s.tag = tagw;
                __hip_atomic_store(base + (size_t)bi * SLOT + t, p.u, __ATOMIC_RELAXED, AGENT);
            }
            // poll: waves 0,1 full; waves 2,3 lanes<16 gather usums (they need vN)
            if (t < 128) {
                bool udone = (l >= 16);
                float usv = 0.f, csum = 0.f;
                for (;;) {
                    PK m[16];
#pragma unroll
                    for (int s = 0; s < 16; s++)
                        m[s].u = __hip_atomic_load(base + (size_t)s * SLOT + t,
                                                   __ATOMIC_RELAXED, AGENT);
                    PK um; um.u = 0ull;
                    if (!udone)
                        um.u = __hip_atomic_load(base + (size_t)l * SLOT + 128,
                                                 __ATOMIC_RELAXED, AGENT);
                    int cnt = 0; float a = 0.f;
#pragma unroll
                    for (int s = 0; s < 16; s++) {
                        bool ok = (m[s].s.tag == tagw);
                        cnt += ok; a += ok ? m[s].s.v : 0.f;
                    }
                    if (!udone && um.s.tag == tagw) { usv = um.s.v; udone = true; }
                    if (cnt == 16 && udone) { csum = a; break; }
                    __builtin_amdgcn_s_sleep(1);
                }
                float ssum = wave_sum(l < 16 ? usv : 0.f);   // all-rows sum of u
                vN = 1.0f / (E * (ssum + uN));
                float vj = 1.0f / (csum + E * uN);
                vbuf[t] = vj;
                float wsm = wave_sum(vj);
                if (l == 0) vbuf[128 + w] = wsm;
            } else {
                bool udone = (l >= 16);
                float usv = 0.f;
                while (!udone) {
                    PK um;
                    um.u = __hip_atomic_load(base + (size_t)l * SLOT + 128,
                                             __ATOMIC_RELAXED, AGENT);
                    if (um.s.tag == tagw) { usv = um.s.v; udone = true; }
                    else __builtin_amdgcn_s_sleep(1);
                }
                float ssum = wave_sum(l < 16 ? usv : 0.f);
                vN = 1.0f / (E * (ssum + uN));  // waves 2,3 need vN for epilogue
            }
            __syncthreads();                // vbuf complete
            vsum = vbuf[128] + vbuf[129];
        }
    }

    // ---------------- phase 4: epilogue P = u_i K0 v_j ----------------
    float* P  = out;                        // [2048][2048]
    float* PA = out + (size_t)2048 * 2048;  // [2049][2049]
    float2 vv = *(const float2*)&vbuf[2 * l];
#pragma unroll 2
    for (int rr2 = 0; rr2 < 32; rr2++) {
        int i = 32 * w + rr2;
        float ui = ubuf[i];
        const char* rp = TrmB + i * 256;
        int c = l >> 2;                     // logical chunk of col 2l
        __half2 h2 = *(const __half2*)(rp + ((c ^ (i & 15)) << 4) + (l & 3) * 4);
        float2 kf = __half22float2(h2);
        float p0 = ui * kf.x * vv.x;
        float p1 = ui * kf.y * vv.y;
        size_t gi = (size_t)(gi0 + i);
        *(float2*)&P[gi * 2048 + gj0 + 2 * l] = make_float2(p0, p1);
        PA[gi * 2049 + gj0 + 2 * l]     = p0;
        PA[gi * 2049 + gj0 + 2 * l + 1] = p1;
        if (bj == 15 && l == 0) PA[gi * 2049 + 2048] = ui * E * vN;     // last col
    }
    if (bi == 15 && w == 0) {               // last row + corner
        PA[(size_t)2048 * 2049 + gj0 + 2 * l]     = uN * E * vv.x;
        PA[(size_t)2048 * 2049 + gj0 + 2 * l + 1] = uN * E * vv.y;
        if (bj == 15 && l == 0) PA[(size_t)2048 * 2049 + 2048] = uN * E * vN;
    }
}

extern "C" void kernel_launch(void* const* d_in, const int* in_sizes, int n_in,
                              void* d_out, int out_size, void* d_ws, size_t ws_size,
                              hipStream_t stream)
{
    (void)in_sizes; (void)n_in; (void)out_size; (void)ws_size;
    const float* Q  = (const float*)d_in[0];
    const float* R  = (const float*)d_in[1];
    const float* zp = (const float*)d_in[2];
    float* out = (float*)d_out;
    unsigned long long* ws = (unsigned long long*)d_ws;
    void* args[] = { (void*)&Q, (void*)&R, (void*)&zp, (void*)&out, (void*)&ws };
    // 256 blocks == 256 CUs, 64 KiB LDS, 1 block/CU -> co-resident for spin-wait.
    // No memset needed: iteration tags (1..100) self-validate against 0xAA poison.
    hipLaunchCooperativeKernel((const void*)sinkhorn_fused, dim3(256), dim3(256),
                               args, 0, stream);
}